// Round 6
// baseline (631.149 us; speedup 1.0000x reference)
//
#include <hip/hip_runtime.h>

// Point2Voxel: scatter-mean of point features into a B x 64^3 voxel grid.
// Outputs (flat, in order): masked_pc[N*3], voxel_feats[B*V*32],
// voxel_counts[B*V], inst_flag[B]  -- all float32.
//
// Binning matches XLA's compiled arithmetic: `t / 0.05` canonicalized to
// `t * 20.0f` (separate f32 roundings, NO FMA -> contract(off) LOAD-BEARING).
// Evidence: R2 (f32 div) 2.36, R3 (f64 div) 2.80, R4 (mul) PASS 0.0039.
//
// R6 scheme: gather, not scatter. Per-voxel linked lists (atomicExch push)
// built in ws; one gather kernel writes every feats/counts byte EXACTLY once.
//
// R7 NEUTRAL: inst_flag hot-line theory falsified.
// R8 PROBE: gather warm cost = 121.8us (ideal ~45-67us).
// R9 PROBE: build cost = ~43us (ideal ~8us).
// R11: nt loads/stores = -15.7us (449.9). Write-allocate theory MOSTLY
//   falsified (predicted -35..-60). Ledger: harness floor ~230us; our
//   kernels ~215us vs ~69us ideal -> 3x excess, cause UNKNOWN.
//
// R12 (this round): COUNTER-VISIBILITY PROBE. Our kernels are <178us and
// invisible below the top-5 fill rows (178-185us). Launch a DOUBLE-PASS
// gather clone into ws scratch (~245us > 185us) -> it surfaces in top-5
// WITH counters. Decision grid:
//   FETCH >> 180MB            -> write-allocate real, nt ineffective -> asm nt/sc1
//   low hbm & low VALUBusy    -> latency-bound chase -> CSR rewrite
//   hbm >60%, traffic ~ model -> gather BW-bound; attack build / accept
// Real outputs unchanged (clone reads head/nxt/feat read-only, writes ws).
// REMOVE PROBE next round.

static constexpr int kNX  = 64;
static constexpr int kNYZ = 64 * 64;
static constexpr int kV   = 64 * 64 * 64;
static constexpr int kB   = 8;
static constexpr int kC   = 32;

typedef float f32x4 __attribute__((ext_vector_type(4)));  // nt-able float4

// ---------------- fast path: linked-list gather ----------------

// Kernel A: per-point. masked_pc, validity, list push, inst_flag.
__global__ void __launch_bounds__(256) p2v_build(
    const float* __restrict__ pc, const int* __restrict__ bid,
    float* __restrict__ masked_pc, int* __restrict__ head,
    int* __restrict__ nxt, float* __restrict__ inst_flag, int n)
{
#pragma clang fp contract(off) reassociate(off)
  int i = blockIdx.x * blockDim.x + threadIdx.x;
  if (i >= n) return;

  const float HALF     = (float)(0.5 * 64 * 0.05);  // 1.60000002384f
  const float INV_UNIT = 20.0f;                      // XLA: /0.05 -> *20.0f

  float x = pc[3 * i + 0];
  float y = pc[3 * i + 1];
  float z = pc[3 * i + 2];
  int   b = bid[i];

  bool valid = (fabsf(x) <= HALF) && (fabsf(y) <= HALF) && (fabsf(z) <= HALF);

  __builtin_nontemporal_store(valid ? x : 0.0f, masked_pc + 3 * i + 0);
  __builtin_nontemporal_store(valid ? y : 0.0f, masked_pc + 3 * i + 1);
  __builtin_nontemporal_store(valid ? z : 0.0f, masked_pc + 3 * i + 2);

  if (!valid) return;

  float tx = x + HALF;
  float ty = y + HALF;
  float tz = z + HALF;
  int ix = (int)(tx * INV_UNIT);
  int iy = (int)(ty * INV_UNIT);
  int iz = (int)(tz * INV_UNIT);
  ix = min(max(ix, 0), kNX - 1);
  iy = min(max(iy, 0), kNX - 1);
  iz = min(max(iz, 0), kNX - 1);

  int lin = b * kV + ix * kNYZ + iy * kNX + iz;
  // Gather runs in a later kernel (full barrier between) -> nt store of nxt
  // is safe relative to the atomicExch publish.
  __builtin_nontemporal_store(atomicExch(head + lin, i), nxt + i);
  inst_flag[b] = 1.0f;  // benign race: same value (R7: aggregation neutral)
}

// Kernel B: gather. 8 lanes per voxel, each lane owns 4 channels (float4).
__global__ void __launch_bounds__(256) p2v_gather(
    const float* __restrict__ feat, const int* __restrict__ head,
    const int* __restrict__ nxt, float* __restrict__ voxel_feats,
    float* __restrict__ voxel_counts)
{
#pragma clang fp contract(off) reassociate(off)
  int gid = blockIdx.x * blockDim.x + threadIdx.x;  // < B*V*8
  int v  = gid >> 3;
  int c4 = (gid & 7) * 4;
  if (v >= kB * kV) return;

  f32x4 sum = (f32x4)(0.0f);
  int cnt = 0;
  int h = head[v];
  while (h >= 0) {
    const f32x4 f =
        __builtin_nontemporal_load((const f32x4*)(feat + (size_t)h * kC + c4));
    sum.x += f.x; sum.y += f.y; sum.z += f.z; sum.w += f.w;
    ++cnt;
    h = nxt[h];
  }

  if (cnt >= 2) {
    double dc = (double)cnt;  // IEEE f32-equivalent quotient via double
    sum.x = (float)((double)sum.x / dc);
    sum.y = (float)((double)sum.y / dc);
    sum.z = (float)((double)sum.z / dc);
    sum.w = (float)((double)sum.w / dc);
  }
  __builtin_nontemporal_store(sum, (f32x4*)(voxel_feats + (size_t)v * kC + c4));

  if (c4 == 0) __builtin_nontemporal_store((float)cnt, voxel_counts + v);
}

// R12 probe: identical chase executed TWICE (two scratch destinations) so a
// single dispatch exceeds the 185us top-5 cutoff and surfaces full counters.
__global__ void __launch_bounds__(256) p2v_gather_probe2(
    const float* __restrict__ feat, const int* __restrict__ head,
    const int* __restrict__ nxt, float* __restrict__ s_feats0,
    float* __restrict__ s_counts0, float* __restrict__ s_feats1,
    float* __restrict__ s_counts1)
{
#pragma clang fp contract(off) reassociate(off)
  int gid = blockIdx.x * blockDim.x + threadIdx.x;
  int v  = gid >> 3;
  int c4 = (gid & 7) * 4;
  if (v >= kB * kV) return;

  for (int p = 0; p < 2; ++p) {
    float* vf = p ? s_feats1 : s_feats0;
    float* vc = p ? s_counts1 : s_counts0;
    f32x4 sum = (f32x4)(0.0f);
    int cnt = 0;
    int h = head[v];
    while (h >= 0) {
      const f32x4 f =
          __builtin_nontemporal_load((const f32x4*)(feat + (size_t)h * kC + c4));
      sum.x += f.x; sum.y += f.y; sum.z += f.z; sum.w += f.w;
      ++cnt;
      h = nxt[h];
    }
    if (cnt >= 2) {
      double dc = (double)cnt;
      sum.x = (float)((double)sum.x / dc);
      sum.y = (float)((double)sum.y / dc);
      sum.z = (float)((double)sum.z / dc);
      sum.w = (float)((double)sum.w / dc);
    }
    __builtin_nontemporal_store(sum, (f32x4*)(vf + (size_t)v * kC + c4));
    if (c4 == 0) __builtin_nontemporal_store((float)cnt, vc + v);
  }
}

// ---------------- fallback path (ws too small): R4/R5 atomic scheme --------

__global__ void __launch_bounds__(256) p2v_main_fb(
    const float* __restrict__ pc, const float* __restrict__ feat,
    const int* __restrict__ bid, float* __restrict__ masked_pc,
    float* __restrict__ voxel_feats, float* __restrict__ voxel_counts,
    float* __restrict__ inst_flag, int n)
{
#pragma clang fp contract(off) reassociate(off)
  int i = blockIdx.x * blockDim.x + threadIdx.x;
  if (i >= n) return;
  const float HALF = (float)(0.5 * 64 * 0.05);
  const float INV_UNIT = 20.0f;
  float x = pc[3 * i + 0], y = pc[3 * i + 1], z = pc[3 * i + 2];
  bool valid = (fabsf(x) <= HALF) && (fabsf(y) <= HALF) && (fabsf(z) <= HALF);
  masked_pc[3 * i + 0] = valid ? x : 0.0f;
  masked_pc[3 * i + 1] = valid ? y : 0.0f;
  masked_pc[3 * i + 2] = valid ? z : 0.0f;
  if (!valid) return;
  int ix = (int)((x + HALF) * INV_UNIT);
  int iy = (int)((y + HALF) * INV_UNIT);
  int iz = (int)((z + HALF) * INV_UNIT);
  ix = min(max(ix, 0), kNX - 1);
  iy = min(max(iy, 0), kNX - 1);
  iz = min(max(iz, 0), kNX - 1);
  int b = bid[i];
  size_t lin = (size_t)b * kV + (size_t)(ix * kNYZ + iy * kNX + iz);
  atomicAdd(voxel_counts + lin, 1.0f);
  inst_flag[b] = 1.0f;
  float* dst = voxel_feats + lin * kC;
  const float* src = feat + (size_t)i * kC;
#pragma unroll
  for (int c = 0; c < kC; ++c) atomicAdd(dst + c, src[c]);
}

__global__ void __launch_bounds__(256) p2v_finalize_fb(
    float* __restrict__ voxel_feats, const float* __restrict__ voxel_counts)
{
#pragma clang fp contract(off) reassociate(off)
  int v = blockIdx.x * blockDim.x + threadIdx.x;
  if (v >= kB * kV) return;
  float c = voxel_counts[v];
  if (c >= 2.0f) {
    float* p = voxel_feats + (size_t)v * kC;
#pragma unroll
    for (int k = 0; k < kC; ++k) p[k] = (float)((double)p[k] / (double)c);
  }
}

// ---------------------------------------------------------------------------

extern "C" void kernel_launch(void* const* d_in, const int* in_sizes, int n_in,
                              void* d_out, int out_size, void* d_ws, size_t ws_size,
                              hipStream_t stream) {
  const float* pc   = (const float*)d_in[0];
  const float* feat = (const float*)d_in[1];
  const int*   bid  = (const int*)d_in[2];
  float* out = (float*)d_out;

  int n = in_sizes[0] / 3;

  float* masked_pc    = out;
  float* voxel_feats  = out + (size_t)3 * n;
  float* voxel_counts = voxel_feats + (size_t)kB * kV * kC;
  float* inst_flag    = voxel_counts + (size_t)kB * kV;

  const int block = 256;
  size_t need = (size_t)kB * kV * sizeof(int) + (size_t)n * sizeof(int);

  if (ws_size >= need) {
    // Fast path: linked-list gather.
    int* head = (int*)d_ws;              // B*V ints (8 MB)
    int* nxt  = head + (size_t)kB * kV;  // n ints (4 MB)

    (void)hipMemsetAsync(head, 0xFF, (size_t)kB * kV * sizeof(int), stream);
    (void)hipMemsetAsync(inst_flag, 0, kB * sizeof(float), stream);

    p2v_build<<<(n + block - 1) / block, block, 0, stream>>>(
        pc, bid, masked_pc, head, nxt, inst_flag, n);

    long long ng = (long long)kB * kV * 8;  // 8 lanes per voxel
    p2v_gather<<<(int)((ng + block - 1) / block), block, 0, stream>>>(
        feat, head, nxt, voxel_feats, voxel_counts);

    // ---- R12 PROBE (remove next round): double-pass clone into ws scratch.
    size_t probe_off = ((size_t)kB * kV + (size_t)n) * sizeof(int);
    probe_off = (probe_off + 255) & ~(size_t)255;
    size_t half = ((size_t)kB * kV * kC + (size_t)kB * kV) * sizeof(float);
    half = (half + 255) & ~(size_t)255;
    if (ws_size >= probe_off + 2 * half) {
      char* base = (char*)d_ws + probe_off;
      float* s_feats0  = (float*)base;
      float* s_counts0 = s_feats0 + (size_t)kB * kV * kC;
      float* s_feats1  = (float*)(base + half);
      float* s_counts1 = s_feats1 + (size_t)kB * kV * kC;
      p2v_gather_probe2<<<(int)((ng + block - 1) / block), block, 0, stream>>>(
          feat, head, nxt, s_feats0, s_counts0, s_feats1, s_counts1);
    }
    // ---- end probe ----
  } else {
    // Fallback: proven R5 atomic scheme (needs no ws).
    size_t tail_floats = (size_t)kB * kV * kC + (size_t)kB * kV + kB;
    (void)hipMemsetAsync(voxel_feats, 0, tail_floats * sizeof(float), stream);
    p2v_main_fb<<<(n + block - 1) / block, block, 0, stream>>>(
        pc, feat, bid, masked_pc, voxel_feats, voxel_counts, inst_flag, n);
    int nv = kB * kV;
    p2v_finalize_fb<<<(nv + block - 1) / block, block, 0, stream>>>(
        voxel_feats, voxel_counts);
  }
}

// Round 7
// 425.871 us; speedup vs baseline: 1.4820x; 1.4820x over previous
//
#include <hip/hip_runtime.h>

// Point2Voxel: scatter-mean of point features into a B x 64^3 voxel grid.
// Outputs (flat, in order): masked_pc[N*3], voxel_feats[B*V*32],
// voxel_counts[B*V], inst_flag[B]  -- all float32.
//
// Binning matches XLA's compiled arithmetic: `t / 0.05` canonicalized to
// `t * 20.0f` (separate f32 roundings, NO FMA -> contract(off) LOAD-BEARING).
// Evidence: R2 (f32 div) 2.36, R3 (f64 div) 2.80, R4 (mul) PASS 0.0039.
//
// R6 scheme: gather, not scatter. Per-voxel linked lists (atomicExch push)
// built in ws; gather writes every feats/counts byte EXACTLY once.
//
// R7 NEUTRAL: inst_flag hot-line theory falsified.
// R8 PROBE: gather warm cost = 121.8us (ideal ~60us).
// R9 PROBE: build cost = ~43us (ideal ~8us).
// R11: nt loads/stores -15.7us (449.9). Write-allocate mostly falsified.
// R12 PROBE (gather counters, finally): hbm 45%, VALUBusy 23%, occ 74%,
//   WRITE 2x275MB exact, FETCH 102MB (pass2 LLC-warm). Diagnosis:
//   LATENCY-BOUND - every thread's first act is a dependent head[v] load
//   (~500-900cy); 16.8M threads / 524K resident = 32 serial generations;
//   MLP~1. ~80us exposed latency per 2 passes.
//
// R13 (this round): 4-voxel-per-thread G-strided batching. Thread q handles
// voxels {q, q+G, q+2G, q+3G} (G=NV/4): 4 head loads in flight (4x MLP on
// the critical latency), 4x fewer thread-generations (32->8). Per-wave store
// coalescing UNCHANGED (each store instruction still covers 8 consecutive
// voxels = 1KB contiguous). Chain walk order per voxel unchanged -> outputs
// bit-identical to R11. Probe removed.
// Predict 449.9 -> 410-430. If <10us delta: falsified -> nt-store-BW probe
// (store-only clone >185us to read its ceiling) or CSR.

static constexpr int kNX  = 64;
static constexpr int kNYZ = 64 * 64;
static constexpr int kV   = 64 * 64 * 64;
static constexpr int kB   = 8;
static constexpr int kC   = 32;
static constexpr int kNV  = kB * kV;      // 2,097,152 voxels
static constexpr int kVB  = 4;            // voxels per gather thread
static constexpr int kG   = kNV / kVB;    // 524,288 (stride between them)

typedef float f32x4 __attribute__((ext_vector_type(4)));  // nt-able float4

// ---------------- fast path: linked-list gather ----------------

// Kernel A: per-point. masked_pc, validity, list push, inst_flag.
__global__ void __launch_bounds__(256) p2v_build(
    const float* __restrict__ pc, const int* __restrict__ bid,
    float* __restrict__ masked_pc, int* __restrict__ head,
    int* __restrict__ nxt, float* __restrict__ inst_flag, int n)
{
#pragma clang fp contract(off) reassociate(off)
  int i = blockIdx.x * blockDim.x + threadIdx.x;
  if (i >= n) return;

  const float HALF     = (float)(0.5 * 64 * 0.05);  // 1.60000002384f
  const float INV_UNIT = 20.0f;                      // XLA: /0.05 -> *20.0f

  float x = pc[3 * i + 0];
  float y = pc[3 * i + 1];
  float z = pc[3 * i + 2];
  int   b = bid[i];

  bool valid = (fabsf(x) <= HALF) && (fabsf(y) <= HALF) && (fabsf(z) <= HALF);

  __builtin_nontemporal_store(valid ? x : 0.0f, masked_pc + 3 * i + 0);
  __builtin_nontemporal_store(valid ? y : 0.0f, masked_pc + 3 * i + 1);
  __builtin_nontemporal_store(valid ? z : 0.0f, masked_pc + 3 * i + 2);

  if (!valid) return;

  float tx = x + HALF;
  float ty = y + HALF;
  float tz = z + HALF;
  int ix = (int)(tx * INV_UNIT);
  int iy = (int)(ty * INV_UNIT);
  int iz = (int)(tz * INV_UNIT);
  ix = min(max(ix, 0), kNX - 1);
  iy = min(max(iy, 0), kNX - 1);
  iz = min(max(iz, 0), kNX - 1);

  int lin = b * kV + ix * kNYZ + iy * kNX + iz;
  // Gather runs in a later kernel (full barrier between) -> nt store of nxt
  // is safe relative to the atomicExch publish.
  __builtin_nontemporal_store(atomicExch(head + lin, i), nxt + i);
  inst_flag[b] = 1.0f;  // benign race: same value (R7: aggregation neutral)
}

// Kernel B: gather, 4 voxels per thread (G-strided), 8 lanes per voxel slot,
// each lane owns 4 channels. The 4 head loads issue together (MLP=4 on the
// dominant latency); chain walks remain per-voxel sequential (chains are
// short: mean 0.34 points/voxel). Wave-level store coalescing identical to
// the 1-voxel version: per unrolled k, a wave writes 8 consecutive voxels.
__global__ void __launch_bounds__(256) p2v_gather4(
    const float* __restrict__ feat, const int* __restrict__ head,
    const int* __restrict__ nxt, float* __restrict__ voxel_feats,
    float* __restrict__ voxel_counts)
{
#pragma clang fp contract(off) reassociate(off)
  int gid = blockIdx.x * blockDim.x + threadIdx.x;  // < kG*8
  int q  = gid >> 3;
  int c4 = (gid & 7) * 4;
  if (q >= kG) return;

  int h0[kVB];
#pragma unroll
  for (int k = 0; k < kVB; ++k) h0[k] = head[q + k * kG];  // 4 loads in flight

#pragma unroll
  for (int k = 0; k < kVB; ++k) {
    int v = q + k * kG;
    f32x4 sum = (f32x4)(0.0f);
    int cnt = 0;
    int h = h0[k];
    while (h >= 0) {
      const f32x4 f = __builtin_nontemporal_load(
          (const f32x4*)(feat + (size_t)h * kC + c4));
      sum.x += f.x; sum.y += f.y; sum.z += f.z; sum.w += f.w;
      ++cnt;
      h = nxt[h];
    }

    if (cnt >= 2) {
      double dc = (double)cnt;  // IEEE f32-equivalent quotient via double
      sum.x = (float)((double)sum.x / dc);
      sum.y = (float)((double)sum.y / dc);
      sum.z = (float)((double)sum.z / dc);
      sum.w = (float)((double)sum.w / dc);
    }
    __builtin_nontemporal_store(sum,
                                (f32x4*)(voxel_feats + (size_t)v * kC + c4));
    if (c4 == 0) __builtin_nontemporal_store((float)cnt, voxel_counts + v);
  }
}

// ---------------- fallback path (ws too small): R4/R5 atomic scheme --------

__global__ void __launch_bounds__(256) p2v_main_fb(
    const float* __restrict__ pc, const float* __restrict__ feat,
    const int* __restrict__ bid, float* __restrict__ masked_pc,
    float* __restrict__ voxel_feats, float* __restrict__ voxel_counts,
    float* __restrict__ inst_flag, int n)
{
#pragma clang fp contract(off) reassociate(off)
  int i = blockIdx.x * blockDim.x + threadIdx.x;
  if (i >= n) return;
  const float HALF = (float)(0.5 * 64 * 0.05);
  const float INV_UNIT = 20.0f;
  float x = pc[3 * i + 0], y = pc[3 * i + 1], z = pc[3 * i + 2];
  bool valid = (fabsf(x) <= HALF) && (fabsf(y) <= HALF) && (fabsf(z) <= HALF);
  masked_pc[3 * i + 0] = valid ? x : 0.0f;
  masked_pc[3 * i + 1] = valid ? y : 0.0f;
  masked_pc[3 * i + 2] = valid ? z : 0.0f;
  if (!valid) return;
  int ix = (int)((x + HALF) * INV_UNIT);
  int iy = (int)((y + HALF) * INV_UNIT);
  int iz = (int)((z + HALF) * INV_UNIT);
  ix = min(max(ix, 0), kNX - 1);
  iy = min(max(iy, 0), kNX - 1);
  iz = min(max(iz, 0), kNX - 1);
  int b = bid[i];
  size_t lin = (size_t)b * kV + (size_t)(ix * kNYZ + iy * kNX + iz);
  atomicAdd(voxel_counts + lin, 1.0f);
  inst_flag[b] = 1.0f;
  float* dst = voxel_feats + lin * kC;
  const float* src = feat + (size_t)i * kC;
#pragma unroll
  for (int c = 0; c < kC; ++c) atomicAdd(dst + c, src[c]);
}

__global__ void __launch_bounds__(256) p2v_finalize_fb(
    float* __restrict__ voxel_feats, const float* __restrict__ voxel_counts)
{
#pragma clang fp contract(off) reassociate(off)
  int v = blockIdx.x * blockDim.x + threadIdx.x;
  if (v >= kB * kV) return;
  float c = voxel_counts[v];
  if (c >= 2.0f) {
    float* p = voxel_feats + (size_t)v * kC;
#pragma unroll
    for (int k = 0; k < kC; ++k) p[k] = (float)((double)p[k] / (double)c);
  }
}

// ---------------------------------------------------------------------------

extern "C" void kernel_launch(void* const* d_in, const int* in_sizes, int n_in,
                              void* d_out, int out_size, void* d_ws, size_t ws_size,
                              hipStream_t stream) {
  const float* pc   = (const float*)d_in[0];
  const float* feat = (const float*)d_in[1];
  const int*   bid  = (const int*)d_in[2];
  float* out = (float*)d_out;

  int n = in_sizes[0] / 3;

  float* masked_pc    = out;
  float* voxel_feats  = out + (size_t)3 * n;
  float* voxel_counts = voxel_feats + (size_t)kB * kV * kC;
  float* inst_flag    = voxel_counts + (size_t)kB * kV;

  const int block = 256;
  size_t need = (size_t)kB * kV * sizeof(int) + (size_t)n * sizeof(int);

  if (ws_size >= need) {
    // Fast path: linked-list gather.
    int* head = (int*)d_ws;              // B*V ints (8 MB)
    int* nxt  = head + (size_t)kB * kV;  // n ints (4 MB)

    (void)hipMemsetAsync(head, 0xFF, (size_t)kB * kV * sizeof(int), stream);
    (void)hipMemsetAsync(inst_flag, 0, kB * sizeof(float), stream);

    p2v_build<<<(n + block - 1) / block, block, 0, stream>>>(
        pc, bid, masked_pc, head, nxt, inst_flag, n);

    long long ng = (long long)kG * 8;  // 8 lanes x NV/4 voxel-quads
    p2v_gather4<<<(int)((ng + block - 1) / block), block, 0, stream>>>(
        feat, head, nxt, voxel_feats, voxel_counts);
  } else {
    // Fallback: proven R5 atomic scheme (needs no ws).
    size_t tail_floats = (size_t)kB * kV * kC + (size_t)kB * kV + kB;
    (void)hipMemsetAsync(voxel_feats, 0, tail_floats * sizeof(float), stream);
    p2v_main_fb<<<(n + block - 1) / block, block, 0, stream>>>(
        pc, feat, bid, masked_pc, voxel_feats, voxel_counts, inst_flag, n);
    int nv = kB * kV;
    p2v_finalize_fb<<<(nv + block - 1) / block, block, 0, stream>>>(
        voxel_feats, voxel_counts);
  }
}